// Round 7
// baseline (671.875 us; speedup 1.0000x reference)
//
#include <hip/hip_runtime.h>
#include <stdint.h>
#include <stddef.h>

#define TOK 8192
#define H 1024
#define IDIM 2048
#define NE 32
#define BM 128
#define BN 128
#define BK 64
#define MAX_TILES 96

typedef __attribute__((ext_vector_type(8))) short short8;
typedef __attribute__((ext_vector_type(4))) float f32x4;
typedef __attribute__((ext_vector_type(4))) float float4v;
typedef __attribute__((ext_vector_type(4))) unsigned int uint4v;

// ---- helpers -------------------------------------------------------------

__device__ __forceinline__ unsigned short f2bf(float x) {   // RNE fp32->bf16
  unsigned u = __builtin_bit_cast(unsigned, x);
  u += 0x7fffu + ((u >> 16) & 1u);
  return (unsigned short)(u >> 16);
}

// async global->LDS, 16B per lane; LDS dest = wave-uniform base + lane*16
__device__ __forceinline__ void gll16(const void* g, void* l) {
  __builtin_amdgcn_global_load_lds(
      (const __attribute__((address_space(1))) unsigned int*)g,
      (__attribute__((address_space(3))) unsigned int*)l, 16, 0, 0);
}

__device__ __forceinline__ f32x4 mfma16(short8 a, short8 b, f32x4 c) {
  return __builtin_amdgcn_mfma_f32_16x16x32_bf16(a, b, c, 0, 0, 0);
}

// W-LDS slot swizzle: sigma(n) = (n ^ (n>>2)) & 7, byte offset sigma<<4.
// 2-way (free) on frag reads (n varies by 1 over 16 lanes) AND on the
// transposed b128 writes (n = wc*4+j, wc varies: sigma(4l+j) distinct per l&7).
__device__ __forceinline__ int wswz(int n) {
  return ((n ^ (n >> 2)) & 7) << 4;
}

// ---- 1) router: logits, top-1, sigmoid, bf16 casts ----------------------

__global__ __launch_bounds__(256) void router_kernel(
    const float* __restrict__ x, const float* __restrict__ gw,
    unsigned short* __restrict__ xbf, unsigned short* __restrict__ xsbf,
    int* __restrict__ expert_id, int* __restrict__ counts)
{
  __shared__ float xl[8 * H];          // 8 token rows, 32KB
  __shared__ float plog[8][8][NE];     // [chunk][tok][e]
  __shared__ float sscore[8];
  const int tid = threadIdx.x;
  const long t0 = (long)blockIdx.x * 8;

  const float4v* src = (const float4v*)(x + t0 * H);
  float4v* dst = (float4v*)xl;
  #pragma unroll
  for (int i = 0; i < 8; ++i) dst[tid + i * 256] = src[tid + i * 256];
  __syncthreads();

  {
    const int e = tid & 31, c = tid >> 5;
    float acc[8] = {0, 0, 0, 0, 0, 0, 0, 0};
    const float* gp = gw + (c * 128) * NE + e;
    for (int h = 0; h < 128; ++h) {
      float g = gp[h * NE];
      const float* xr = xl + (c * 128 + h);
      #pragma unroll
      for (int tk = 0; tk < 8; ++tk) acc[tk] += xr[tk * H] * g;
    }
    #pragma unroll
    for (int tk = 0; tk < 8; ++tk) plog[c][tk][e] = acc[tk];
  }
  __syncthreads();
  {
    const int e = tid & 31, tok = tid >> 5;
    float lg = 0.f;
    #pragma unroll
    for (int c = 0; c < 8; ++c) lg += plog[c][tok][e];
    float m = lg; int be = e;
    #pragma unroll
    for (int mask = 16; mask >= 1; mask >>= 1) {   // reduce within 32-lane group
      float om = __shfl_xor(m, mask);
      int   oe = __shfl_xor(be, mask);
      if (om > m || (om == m && oe < be)) { m = om; be = oe; }  // first-index tie
    }
    if (e == 0) {
      sscore[tok] = 1.f / (1.f + __expf(-m));
      expert_id[t0 + tok] = be;
      atomicAdd(&counts[be], 1);
    }
  }
  __syncthreads();
  {
    const float sc = sscore[tid >> 5];
    const int base = (tid >> 5) * H + (tid & 31) * 32;
    #pragma unroll
    for (int i = 0; i < 4; ++i) {
      short8 vx, vs;
      #pragma unroll
      for (int j = 0; j < 8; ++j) {
        float v = xl[base + i * 8 + j];
        vx[j] = (short)f2bf(v);
        vs[j] = (short)f2bf(v * sc);
      }
      *(short8*)(xbf  + t0 * H + base + i * 8) = vx;
      *(short8*)(xsbf + t0 * H + base + i * 8) = vs;
    }
  }
}

// ---- 2) scan: offsets, cursors, tile table ------------------------------

__global__ void scan_kernel(const int* __restrict__ counts, int* __restrict__ offsets,
                            int* __restrict__ cursor, int* __restrict__ tile_e,
                            int* __restrict__ tile_p, int* __restrict__ n_tiles)
{
  if (threadIdx.x != 0) return;
  int off = 0, nt = 0;
  for (int e = 0; e < NE; ++e) {
    offsets[e] = off; cursor[e] = off;
    int cc = counts[e];
    for (int k = 0; k < cc; k += BM) { tile_e[nt] = e; tile_p[nt] = off + k; ++nt; }
    off += cc;
  }
  offsets[NE] = off;
  n_tiles[0] = nt;
}

// ---- 3) perm build -------------------------------------------------------

__global__ __launch_bounds__(256) void perm_kernel(
    const int* __restrict__ expert_id, int* __restrict__ cursor, int* __restrict__ perm)
{
  int t = blockIdx.x * 256 + threadIdx.x;
  int e = expert_id[t];
  int pos = atomicAdd(&cursor[e], 1);
  perm[pos] = t;
}

// ---- 4) fused gate+up GEMM -> act = bf16(silu(xWg) * xWu) ---------------
// BM=128 x BN=128, BK=64, 4 waves in 2x2, wave tile 64x64 (m=4,n=4 frags).
// LDS reads/FLOP cut 1.67x vs 32x64 wave tile (LDS-BW was the measured pipe).
// Round-4 2-barrier loop: stage A(t+1) via gll16 + W(t+1)->regs before
// compute(t); barrier; cvt+ds_write W; barrier.
// W staged per thread as an 8k x 4n block -> 4 transposed b128 LDS writes.

template<bool ROUTED>
__global__ __launch_bounds__(256, 2) void gateup_kernel(
    const unsigned short* __restrict__ Abase,
    const float* __restrict__ WgAll, const float* __restrict__ WuAll,
    unsigned short* __restrict__ act,
    const int* __restrict__ perm, const int* __restrict__ tile_e,
    const int* __restrict__ tile_p, const int* __restrict__ offsets,
    const int* __restrict__ n_tiles)
{
  __shared__ short Alds[2][BM * BK];  // 2x16KB, [row][k], byte^=(row&7)<<4
  __shared__ short Glds[BN * BK];     // 16KB, [n][k] wswz
  __shared__ short Ulds[BN * BK];     // 16KB  (64KB total -> 2 blocks/CU)

  const int tid = threadIdx.x;
  const int wave = tid >> 6, lane = tid & 63;
  const int wm = wave >> 1, wn = wave & 1;   // 2x2 wave grid

  int row0, row_end;
  const float *Wg, *Wu;
  if constexpr (ROUTED) {
    if ((int)blockIdx.x >= *n_tiles) return;
    const int e = tile_e[blockIdx.x];
    row0 = tile_p[blockIdx.x];
    row_end = offsets[e + 1];
    Wg = WgAll + (size_t)e * H * IDIM;
    Wu = WuAll + (size_t)e * H * IDIM;
  } else {
    row0 = blockIdx.x * BM; row_end = row0 + BM;
    Wg = WgAll; Wu = WuAll;
  }
  const int n0 = blockIdx.y * BN;

  // A staging: wave w stages rows [32w, 32w+32) (4 gll16); barriers separate
  // staging from the cross-wave reads.
  const unsigned short* asrc[4];
  int aoff[4];
  #pragma unroll
  for (int i = 0; i < 4; ++i) {
    const int r = wave * 32 + i * 8 + (lane >> 3);
    int grow;
    if constexpr (ROUTED) {
      int p = row0 + r;
      if (p >= row_end) p = row0;
      grow = perm[p];
    } else grow = row0 + r;
    const int cb = ((lane & 7) * 16) ^ ((r & 7) << 4);
    asrc[i] = Abase + (size_t)grow * H + (cb >> 1);
    aoff[i] = (wave * 32 + i * 8) * BK;
  }

  const int wq = tid >> 5;          // 0..7: k-octet (8 rows)
  const int wc = tid & 31;          // 0..31: n-quad

  f32x4 accg[4][4] = {};
  f32x4 accu[4][4] = {};
  float4v g4[8], u4[8];

  auto stageA = [&](int kt) {
    short* base = Alds[kt & 1];
    #pragma unroll
    for (int i = 0; i < 4; ++i) gll16(asrc[i] + kt * BK, base + aoff[i]);
  };
  auto loadW = [&](int kt) {
    const int k0 = kt * BK;
    #pragma unroll
    for (int r = 0; r < 8; ++r) {
      const size_t goff = (size_t)(k0 + wq * 8 + r) * IDIM + (n0 + wc * 4);
      g4[r] = *(const float4v*)(Wg + goff);
      u4[r] = *(const float4v*)(Wu + goff);
    }
  };
  auto writeW = [&]() {
    #pragma unroll
    for (int j = 0; j < 4; ++j) {        // transpose 8x4 -> 4 b128 [n][k] writes
      const int n = wc * 4 + j;
      const int cb = (wq * 16) ^ wswz(n);
      uint4v pg, pu;
      pg.x = (unsigned)f2bf(g4[0][j]) | ((unsigned)f2bf(g4[1][j]) << 16);
      pg.y = (unsigned)f2bf(g4[2][j]) | ((unsigned)f2bf(g4[3][j]) << 16);
      pg.z = (unsigned)f2bf(g4[4][j]) | ((unsigned)f2bf(g4[5][j]) << 16);
      pg.w = (unsigned)f2bf(g4[6][j]) | ((unsigned)f2bf(g4[7][j]) << 16);
      pu.x = (unsigned)f2bf(u4[0][j]) | ((unsigned)f2bf(u4[1][j]) << 16);
      pu.y = (unsigned)f2bf(u4[2][j]) | ((unsigned)f2bf(u4[3][j]) << 16);
      pu.z = (unsigned)f2bf(u4[4][j]) | ((unsigned)f2bf(u4[5][j]) << 16);
      pu.w = (unsigned)f2bf(u4[6][j]) | ((unsigned)f2bf(u4[7][j]) << 16);
      *(uint4v*)((char*)Glds + n * 128 + cb) = pg;
      *(uint4v*)((char*)Ulds + n * 128 + cb) = pu;
    }
  };
  auto compute = [&](int kt) {
    const char* ab = (const char*)Alds[kt & 1];
    #pragma unroll
    for (int kk = 0; kk < 2; ++kk) {
      short8 af[4];
      #pragma unroll
      for (int m = 0; m < 4; ++m) {
        const int r = wm * 64 + m * 16 + (lane & 15);
        const int cb = (kk * 64 + ((lane >> 4) * 16)) ^ ((r & 7) << 4);
        af[m] = *(const short8*)(ab + r * 128 + cb);
      }
      #pragma unroll
      for (int nf = 0; nf < 4; ++nf) {
        const int n = wn * 64 + nf * 16 + (lane & 15);
        const int cb = (kk * 64 + ((lane >> 4) * 16)) ^ wswz(n);
        short8 bg = *(const short8*)((const char*)Glds + n * 128 + cb);
        short8 bu = *(const short8*)((const char*)Ulds + n * 128 + cb);
        #pragma unroll
        for (int m = 0; m < 4; ++m) {
          accg[m][nf] = mfma16(af[m], bg, accg[m][nf]);
          accu[m][nf] = mfma16(af[m], bu, accu[m][nf]);
        }
      }
    }
  };

  // prologue: stage tile 0 fully
  stageA(0);
  loadW(0);
  writeW();
  __syncthreads();

  #pragma unroll 1
  for (int kt = 0; kt < H / BK - 1; ++kt) {
    stageA(kt + 1);                   // async A(t+1) into other buf
    loadW(kt + 1);                    // W(t+1) -> regs under compute(t)
    compute(kt);
    __syncthreads();                  // compute done; A(t+1)+W regs drained
    writeW();                         // land W(t+1) in single W-LDS
    __syncthreads();                  // W(t+1) visible
  }
  compute(H / BK - 1);

  // epilogue: silu(g)*u -> bf16 act
  #pragma unroll
  for (int m = 0; m < 4; ++m)
    #pragma unroll
    for (int nf = 0; nf < 4; ++nf) {
      const int col = n0 + wn * 64 + nf * 16 + (lane & 15);
      #pragma unroll
      for (int j = 0; j < 4; ++j) {
        const int row = row0 + wm * 64 + m * 16 + ((lane >> 4) * 4) + j;
        if (ROUTED && row >= row_end) continue;
        const float g = accg[m][nf][j];
        const float u = accu[m][nf][j];
        const float v = (g / (1.f + __expf(-g))) * u;
        act[(size_t)row * IDIM + col] = f2bf(v);
      }
    }
}

// ---- 5) down GEMM: out = act @ Wd (+ scatter-add for routed) ------------
// Same reshape: BM=128 x BN=128, wave 64x64. LDS 48KB -> 3 blocks/CU.

template<bool ROUTED>
__global__ __launch_bounds__(256, 2) void down_kernel(
    const unsigned short* __restrict__ act,
    const float* __restrict__ WdAll,
    float* __restrict__ out,
    const int* __restrict__ perm, const int* __restrict__ tile_e,
    const int* __restrict__ tile_p, const int* __restrict__ offsets,
    const int* __restrict__ n_tiles)
{
  __shared__ short Alds[2][BM * BK];  // 2x16KB
  __shared__ short Wlds[BN * BK];     // 16KB  (48KB total)

  const int tid = threadIdx.x;
  const int wave = tid >> 6, lane = tid & 63;
  const int wm = wave >> 1, wn = wave & 1;

  int row0, row_end;
  const float* Wd;
  if constexpr (ROUTED) {
    if ((int)blockIdx.x >= *n_tiles) return;
    const int e = tile_e[blockIdx.x];
    row0 = tile_p[blockIdx.x];
    row_end = offsets[e + 1];
    Wd = WdAll + (size_t)e * IDIM * H;
  } else {
    row0 = blockIdx.x * BM; row_end = row0 + BM;
    Wd = WdAll;
  }
  const int n0 = blockIdx.y * BN;

  const unsigned short* asrc[4];
  int aoff[4];
  #pragma unroll
  for (int i = 0; i < 4; ++i) {
    const int r = wave * 32 + i * 8 + (lane >> 3);
    int p = row0 + r;
    if (ROUTED && p >= row_end) p = row0;
    const int cb = ((lane & 7) * 16) ^ ((r & 7) << 4);
    asrc[i] = act + (size_t)p * IDIM + (cb >> 1);   // sorted-order rows
    aoff[i] = (wave * 32 + i * 8) * BK;
  }

  const int wq = tid >> 5;
  const int wc = tid & 31;

  f32x4 acc[4][4] = {};
  float4v w4[8];

  auto stageA = [&](int kt) {
    short* base = Alds[kt & 1];
    #pragma unroll
    for (int i = 0; i < 4; ++i) gll16(asrc[i] + kt * BK, base + aoff[i]);
  };
  auto loadW = [&](int kt) {
    const int k0 = kt * BK;
    #pragma unroll
    for (int r = 0; r < 8; ++r)
      w4[r] = *(const float4v*)(Wd + (size_t)(k0 + wq * 8 + r) * H + (n0 + wc * 4));
  };
  auto writeW = [&]() {
    #pragma unroll
    for (int j = 0; j < 4; ++j) {
      const int n = wc * 4 + j;
      const int cb = (wq * 16) ^ wswz(n);
      uint4v pw;
      pw.x = (unsigned)f2bf(w4[0][j]) | ((unsigned)f2bf(w4[1][j]) << 16);
      pw.y = (unsigned)f2bf(w4[2][j]) | ((unsigned)f2bf(w4[3][j]) << 16);
      pw.z = (unsigned)f2bf(w4[4][j]) | ((unsigned)f2bf(w4[5][j]) << 16);
      pw.w = (unsigned)f2bf(w4[6][j]) | ((unsigned)f2bf(w4[7][j]) << 16);
      *(uint4v*)((char*)Wlds + n * 128 + cb) = pw;
    }
  };
  auto compute = [&](int kt) {
    const char* ab = (const char*)Alds[kt & 1];
    #pragma unroll
    for (int kk = 0; kk < 2; ++kk) {
      short8 af[4];
      #pragma unroll
      for (int m = 0; m < 4; ++m) {
        const int r = wm * 64 + m * 16 + (lane & 15);
        const int cb = (kk * 64 + ((lane >> 4) * 16)) ^ ((r & 7) << 4);
        af[m] = *(const short8*)(ab + r * 128 + cb);
      }
      #pragma unroll
      for (int nf = 0; nf < 4; ++nf) {
        const int n = wn * 64 + nf * 16 + (lane & 15);
        const int cb = (kk * 64 + ((lane >> 4) * 16)) ^ wswz(n);
        short8 bw = *(const short8*)((const char*)Wlds + n * 128 + cb);
        #pragma unroll
        for (int m = 0; m < 4; ++m) acc[m][nf] = mfma16(af[m], bw, acc[m][nf]);
      }
    }
  };

  stageA(0);
  loadW(0);
  writeW();
  __syncthreads();

  #pragma unroll 1
  for (int kt = 0; kt < IDIM / BK - 1; ++kt) {
    stageA(kt + 1);
    loadW(kt + 1);
    compute(kt);
    __syncthreads();
    writeW();
    __syncthreads();
  }
  compute(IDIM / BK - 1);

  #pragma unroll
  for (int m = 0; m < 4; ++m)
    #pragma unroll
    for (int nf = 0; nf < 4; ++nf) {
      const int col = n0 + wn * 64 + nf * 16 + (lane & 15);
      #pragma unroll
      for (int j = 0; j < 4; ++j) {
        const int row = row0 + wm * 64 + m * 16 + ((lane >> 4) * 4) + j;
        const float v = acc[m][nf][j];
        if constexpr (ROUTED) {
          if (row < row_end) {
            const int t = perm[row];
            out[(size_t)t * H + col] += v;     // shared pass wrote first
          }
        } else {
          out[(size_t)row * H + col] = v;
        }
      }
    }
}

// ---- launch --------------------------------------------------------------

extern "C" void kernel_launch(void* const* d_in, const int* in_sizes, int n_in,
                              void* d_out, int out_size, void* d_ws, size_t ws_size,
                              hipStream_t stream) {
  (void)in_sizes; (void)n_in; (void)out_size; (void)ws_size;
  const float* x      = (const float*)d_in[0];
  const float* gate_w = (const float*)d_in[1];
  const float* sgw    = (const float*)d_in[2];
  const float* suw    = (const float*)d_in[3];
  const float* sdw    = (const float*)d_in[4];
  const float* rgw    = (const float*)d_in[5];
  const float* ruw    = (const float*)d_in[6];
  const float* rdw    = (const float*)d_in[7];
  float* out = (float*)d_out;

  char* ws = (char*)d_ws;
  unsigned short* xbf  = (unsigned short*)(ws + 0);           // 16MB
  unsigned short* xsbf = (unsigned short*)(ws + 16777216);    // 16MB
  unsigned short* act  = (unsigned short*)(ws + 33554432);    // 32MB
  int* perm      = (int*)(ws + 67108864);                     // 32KB
  int* expert_id = (int*)(ws + 67141632);                     // 32KB
  int* counts    = (int*)(ws + 67174400);
  int* offsets   = (int*)(ws + 67174528);
  int* cursor    = (int*)(ws + 67174784);
  int* tile_e    = (int*)(ws + 67174912);
  int* tile_p    = (int*)(ws + 67175424);
  int* n_tiles   = (int*)(ws + 67175936);

  hipMemsetAsync(counts, 0, NE * sizeof(int), stream);
  router_kernel<<<TOK / 8, 256, 0, stream>>>(x, gate_w, xbf, xsbf, expert_id, counts);
  scan_kernel<<<1, 64, 0, stream>>>(counts, offsets, cursor, tile_e, tile_p, n_tiles);
  perm_kernel<<<TOK / 256, 256, 0, stream>>>(expert_id, cursor, perm);

  gateup_kernel<false><<<dim3(TOK / BM, IDIM / BN), 256, 0, stream>>>(
      xbf, sgw, suw, act, perm, tile_e, tile_p, offsets, n_tiles);
  down_kernel<false><<<dim3(TOK / BM, H / BN), 256, 0, stream>>>(
      act, sdw, out, perm, tile_e, tile_p, offsets, n_tiles);
  gateup_kernel<true><<<dim3(MAX_TILES, IDIM / BN), 256, 0, stream>>>(
      xsbf, rgw, ruw, act, perm, tile_e, tile_p, offsets, n_tiles);
  down_kernel<true><<<dim3(MAX_TILES, H / BN), 256, 0, stream>>>(
      act, rdw, out, perm, tile_e, tile_p, offsets, n_tiles);
}

// Round 8
// 648.027 us; speedup vs baseline: 1.0368x; 1.0368x over previous
//
#include <hip/hip_runtime.h>
#include <stdint.h>
#include <stddef.h>

#define TOK 8192
#define H 1024
#define IDIM 2048
#define NE 32
#define BM 128
#define BN 128
#define BK 64
#define MAX_TILES 96

typedef __attribute__((ext_vector_type(8))) short short8;
typedef __attribute__((ext_vector_type(4))) float f32x4;
typedef __attribute__((ext_vector_type(4))) float float4v;
typedef __attribute__((ext_vector_type(4))) unsigned int uint4v;

// ---- helpers -------------------------------------------------------------

__device__ __forceinline__ unsigned short f2bf(float x) {   // RNE fp32->bf16
  unsigned u = __builtin_bit_cast(unsigned, x);
  u += 0x7fffu + ((u >> 16) & 1u);
  return (unsigned short)(u >> 16);
}

// HW packed convert: lo -> bits[15:0], hi -> bits[31:16], RNE. 1 VALU inst.
__device__ __forceinline__ unsigned cvtpk(float lo, float hi) {
  unsigned r;
  asm("v_cvt_pk_bf16_f32 %0, %1, %2" : "=v"(r) : "v"(lo), "v"(hi));
  return r;
}

// async global->LDS, 16B per lane; LDS dest = wave-uniform base + lane*16
__device__ __forceinline__ void gll16(const void* g, void* l) {
  __builtin_amdgcn_global_load_lds(
      (const __attribute__((address_space(1))) unsigned int*)g,
      (__attribute__((address_space(3))) unsigned int*)l, 16, 0, 0);
}

__device__ __forceinline__ f32x4 mfma16(short8 a, short8 b, f32x4 c) {
  return __builtin_amdgcn_mfma_f32_16x16x32_bf16(a, b, c, 0, 0, 0);
}

// W-LDS slot swizzle: sigma(n) = (n ^ (n>>2)) & 7, byte offset sigma<<4.
__device__ __forceinline__ int wswz(int n) {
  return ((n ^ (n >> 2)) & 7) << 4;
}

// ---- 1) router: logits, top-1, sigmoid, bf16 casts ----------------------

__global__ __launch_bounds__(256) void router_kernel(
    const float* __restrict__ x, const float* __restrict__ gw,
    unsigned short* __restrict__ xbf, unsigned short* __restrict__ xsbf,
    int* __restrict__ expert_id, int* __restrict__ counts)
{
  __shared__ float xl[8 * H];          // 8 token rows, 32KB
  __shared__ float plog[8][8][NE];     // [chunk][tok][e]
  __shared__ float sscore[8];
  const int tid = threadIdx.x;
  const long t0 = (long)blockIdx.x * 8;

  const float4v* src = (const float4v*)(x + t0 * H);
  float4v* dst = (float4v*)xl;
  #pragma unroll
  for (int i = 0; i < 8; ++i) dst[tid + i * 256] = src[tid + i * 256];
  __syncthreads();

  {
    const int e = tid & 31, c = tid >> 5;
    float acc[8] = {0, 0, 0, 0, 0, 0, 0, 0};
    const float* gp = gw + (c * 128) * NE + e;
    for (int h = 0; h < 128; ++h) {
      float g = gp[h * NE];
      const float* xr = xl + (c * 128 + h);
      #pragma unroll
      for (int tk = 0; tk < 8; ++tk) acc[tk] += xr[tk * H] * g;
    }
    #pragma unroll
    for (int tk = 0; tk < 8; ++tk) plog[c][tk][e] = acc[tk];
  }
  __syncthreads();
  {
    const int e = tid & 31, tok = tid >> 5;
    float lg = 0.f;
    #pragma unroll
    for (int c = 0; c < 8; ++c) lg += plog[c][tok][e];
    float m = lg; int be = e;
    #pragma unroll
    for (int mask = 16; mask >= 1; mask >>= 1) {   // reduce within 32-lane group
      float om = __shfl_xor(m, mask);
      int   oe = __shfl_xor(be, mask);
      if (om > m || (om == m && oe < be)) { m = om; be = oe; }  // first-index tie
    }
    if (e == 0) {
      sscore[tok] = 1.f / (1.f + __expf(-m));
      expert_id[t0 + tok] = be;
      atomicAdd(&counts[be], 1);
    }
  }
  __syncthreads();
  {
    const float sc = sscore[tid >> 5];
    const int base = (tid >> 5) * H + (tid & 31) * 32;
    #pragma unroll
    for (int i = 0; i < 4; ++i) {
      uint4v vx, vs;
      #pragma unroll
      for (int q = 0; q < 4; ++q) {
        const float a = xl[base + i * 8 + 2 * q];
        const float b = xl[base + i * 8 + 2 * q + 1];
        vx[q] = cvtpk(a, b);
        vs[q] = cvtpk(a * sc, b * sc);
      }
      *(uint4v*)(xbf  + t0 * H + base + i * 8) = vx;
      *(uint4v*)(xsbf + t0 * H + base + i * 8) = vs;
    }
  }
}

// ---- 2) scan: offsets, cursors, tile table ------------------------------

__global__ void scan_kernel(const int* __restrict__ counts, int* __restrict__ offsets,
                            int* __restrict__ cursor, int* __restrict__ tile_e,
                            int* __restrict__ tile_p, int* __restrict__ n_tiles)
{
  if (threadIdx.x != 0) return;
  int off = 0, nt = 0;
  for (int e = 0; e < NE; ++e) {
    offsets[e] = off; cursor[e] = off;
    int cc = counts[e];
    for (int k = 0; k < cc; k += BM) { tile_e[nt] = e; tile_p[nt] = off + k; ++nt; }
    off += cc;
  }
  offsets[NE] = off;
  n_tiles[0] = nt;
}

// ---- 3) perm build -------------------------------------------------------

__global__ __launch_bounds__(256) void perm_kernel(
    const int* __restrict__ expert_id, int* __restrict__ cursor, int* __restrict__ perm)
{
  int t = blockIdx.x * 256 + threadIdx.x;
  int e = expert_id[t];
  int pos = atomicAdd(&cursor[e], 1);
  perm[pos] = t;
}

// ---- 4) fused gate+up GEMM -> act = bf16(silu(xWg) * xWu) ---------------
// BM=128 x BN=128, BK=64, 4 waves in 2x2, wave tile 64x64.
// K-loop was VALU-bound on fp32->bf16 convert (f2bf ~6 ops/elem); replaced
// with v_cvt_pk_bf16_f32 (1 inst / 2 elems) -> ~10x fewer convert ops.

template<bool ROUTED>
__global__ __launch_bounds__(256, 2) void gateup_kernel(
    const unsigned short* __restrict__ Abase,
    const float* __restrict__ WgAll, const float* __restrict__ WuAll,
    unsigned short* __restrict__ act,
    const int* __restrict__ perm, const int* __restrict__ tile_e,
    const int* __restrict__ tile_p, const int* __restrict__ offsets,
    const int* __restrict__ n_tiles)
{
  __shared__ short Alds[2][BM * BK];  // 2x16KB, [row][k], byte^=(row&7)<<4
  __shared__ short Glds[BN * BK];     // 16KB, [n][k] wswz
  __shared__ short Ulds[BN * BK];     // 16KB  (64KB total -> 2 blocks/CU)

  const int tid = threadIdx.x;
  const int wave = tid >> 6, lane = tid & 63;
  const int wm = wave >> 1, wn = wave & 1;   // 2x2 wave grid

  int row0, row_end;
  const float *Wg, *Wu;
  if constexpr (ROUTED) {
    if ((int)blockIdx.x >= *n_tiles) return;
    const int e = tile_e[blockIdx.x];
    row0 = tile_p[blockIdx.x];
    row_end = offsets[e + 1];
    Wg = WgAll + (size_t)e * H * IDIM;
    Wu = WuAll + (size_t)e * H * IDIM;
  } else {
    row0 = blockIdx.x * BM; row_end = row0 + BM;
    Wg = WgAll; Wu = WuAll;
  }
  const int n0 = blockIdx.y * BN;

  // A staging: wave w stages rows [32w, 32w+32) (4 gll16).
  const unsigned short* asrc[4];
  int aoff[4];
  #pragma unroll
  for (int i = 0; i < 4; ++i) {
    const int r = wave * 32 + i * 8 + (lane >> 3);
    int grow;
    if constexpr (ROUTED) {
      int p = row0 + r;
      if (p >= row_end) p = row0;
      grow = perm[p];
    } else grow = row0 + r;
    const int cb = ((lane & 7) * 16) ^ ((r & 7) << 4);
    asrc[i] = Abase + (size_t)grow * H + (cb >> 1);
    aoff[i] = (wave * 32 + i * 8) * BK;
  }

  const int wq = tid >> 5;          // 0..7: k-octet (8 rows)
  const int wc = tid & 31;          // 0..31: n-quad

  f32x4 accg[4][4] = {};
  f32x4 accu[4][4] = {};
  float4v g4[8], u4[8];

  auto stageA = [&](int kt) {
    short* base = Alds[kt & 1];
    #pragma unroll
    for (int i = 0; i < 4; ++i) gll16(asrc[i] + kt * BK, base + aoff[i]);
  };
  auto loadW = [&](int kt) {
    const int k0 = kt * BK;
    #pragma unroll
    for (int r = 0; r < 8; ++r) {
      const size_t goff = (size_t)(k0 + wq * 8 + r) * IDIM + (n0 + wc * 4);
      g4[r] = *(const float4v*)(Wg + goff);
      u4[r] = *(const float4v*)(Wu + goff);
    }
  };
  auto writeW = [&]() {
    #pragma unroll
    for (int j = 0; j < 4; ++j) {        // transpose 8x4 -> 4 b128 [n][k] writes
      const int n = wc * 4 + j;
      const int cb = (wq * 16) ^ wswz(n);
      uint4v pg, pu;
      pg.x = cvtpk(g4[0][j], g4[1][j]);
      pg.y = cvtpk(g4[2][j], g4[3][j]);
      pg.z = cvtpk(g4[4][j], g4[5][j]);
      pg.w = cvtpk(g4[6][j], g4[7][j]);
      pu.x = cvtpk(u4[0][j], u4[1][j]);
      pu.y = cvtpk(u4[2][j], u4[3][j]);
      pu.z = cvtpk(u4[4][j], u4[5][j]);
      pu.w = cvtpk(u4[6][j], u4[7][j]);
      *(uint4v*)((char*)Glds + n * 128 + cb) = pg;
      *(uint4v*)((char*)Ulds + n * 128 + cb) = pu;
    }
  };
  auto compute = [&](int kt) {
    const char* ab = (const char*)Alds[kt & 1];
    #pragma unroll
    for (int kk = 0; kk < 2; ++kk) {
      short8 af[4];
      #pragma unroll
      for (int m = 0; m < 4; ++m) {
        const int r = wm * 64 + m * 16 + (lane & 15);
        const int cb = (kk * 64 + ((lane >> 4) * 16)) ^ ((r & 7) << 4);
        af[m] = *(const short8*)(ab + r * 128 + cb);
      }
      #pragma unroll
      for (int nf = 0; nf < 4; ++nf) {
        const int n = wn * 64 + nf * 16 + (lane & 15);
        const int cb = (kk * 64 + ((lane >> 4) * 16)) ^ wswz(n);
        short8 bg = *(const short8*)((const char*)Glds + n * 128 + cb);
        short8 bu = *(const short8*)((const char*)Ulds + n * 128 + cb);
        #pragma unroll
        for (int m = 0; m < 4; ++m) {
          accg[m][nf] = mfma16(af[m], bg, accg[m][nf]);
          accu[m][nf] = mfma16(af[m], bu, accu[m][nf]);
        }
      }
    }
  };

  // prologue: stage tile 0 fully
  stageA(0);
  loadW(0);
  writeW();
  __syncthreads();

  #pragma unroll 1
  for (int kt = 0; kt < H / BK - 1; ++kt) {
    stageA(kt + 1);                   // async A(t+1) into other buf
    loadW(kt + 1);                    // W(t+1) -> regs under compute(t)
    compute(kt);
    __syncthreads();                  // compute done; A(t+1)+W regs drained
    writeW();                         // land W(t+1) in single W-LDS
    __syncthreads();                  // W(t+1) visible
  }
  compute(H / BK - 1);

  // epilogue: silu(g)*u -> bf16 act
  #pragma unroll
  for (int m = 0; m < 4; ++m)
    #pragma unroll
    for (int nf = 0; nf < 4; ++nf) {
      const int col = n0 + wn * 64 + nf * 16 + (lane & 15);
      #pragma unroll
      for (int j = 0; j < 4; ++j) {
        const int row = row0 + wm * 64 + m * 16 + ((lane >> 4) * 4) + j;
        if (ROUTED && row >= row_end) continue;
        const float g = accg[m][nf][j];
        const float u = accu[m][nf][j];
        const float v = (g / (1.f + __expf(-g))) * u;
        act[(size_t)row * IDIM + col] = f2bf(v);
      }
    }
}

// ---- 5) down GEMM: out = act @ Wd (+ scatter-add for routed) ------------

template<bool ROUTED>
__global__ __launch_bounds__(256, 2) void down_kernel(
    const unsigned short* __restrict__ act,
    const float* __restrict__ WdAll,
    float* __restrict__ out,
    const int* __restrict__ perm, const int* __restrict__ tile_e,
    const int* __restrict__ tile_p, const int* __restrict__ offsets,
    const int* __restrict__ n_tiles)
{
  __shared__ short Alds[2][BM * BK];  // 2x16KB
  __shared__ short Wlds[BN * BK];     // 16KB  (48KB total)

  const int tid = threadIdx.x;
  const int wave = tid >> 6, lane = tid & 63;
  const int wm = wave >> 1, wn = wave & 1;

  int row0, row_end;
  const float* Wd;
  if constexpr (ROUTED) {
    if ((int)blockIdx.x >= *n_tiles) return;
    const int e = tile_e[blockIdx.x];
    row0 = tile_p[blockIdx.x];
    row_end = offsets[e + 1];
    Wd = WdAll + (size_t)e * IDIM * H;
  } else {
    row0 = blockIdx.x * BM; row_end = row0 + BM;
    Wd = WdAll;
  }
  const int n0 = blockIdx.y * BN;

  const unsigned short* asrc[4];
  int aoff[4];
  #pragma unroll
  for (int i = 0; i < 4; ++i) {
    const int r = wave * 32 + i * 8 + (lane >> 3);
    int p = row0 + r;
    if (ROUTED && p >= row_end) p = row0;
    const int cb = ((lane & 7) * 16) ^ ((r & 7) << 4);
    asrc[i] = act + (size_t)p * IDIM + (cb >> 1);   // sorted-order rows
    aoff[i] = (wave * 32 + i * 8) * BK;
  }

  const int wq = tid >> 5;
  const int wc = tid & 31;

  f32x4 acc[4][4] = {};
  float4v w4[8];

  auto stageA = [&](int kt) {
    short* base = Alds[kt & 1];
    #pragma unroll
    for (int i = 0; i < 4; ++i) gll16(asrc[i] + kt * BK, base + aoff[i]);
  };
  auto loadW = [&](int kt) {
    const int k0 = kt * BK;
    #pragma unroll
    for (int r = 0; r < 8; ++r)
      w4[r] = *(const float4v*)(Wd + (size_t)(k0 + wq * 8 + r) * H + (n0 + wc * 4));
  };
  auto writeW = [&]() {
    #pragma unroll
    for (int j = 0; j < 4; ++j) {
      const int n = wc * 4 + j;
      const int cb = (wq * 16) ^ wswz(n);
      uint4v pw;
      pw.x = cvtpk(w4[0][j], w4[1][j]);
      pw.y = cvtpk(w4[2][j], w4[3][j]);
      pw.z = cvtpk(w4[4][j], w4[5][j]);
      pw.w = cvtpk(w4[6][j], w4[7][j]);
      *(uint4v*)((char*)Wlds + n * 128 + cb) = pw;
    }
  };
  auto compute = [&](int kt) {
    const char* ab = (const char*)Alds[kt & 1];
    #pragma unroll
    for (int kk = 0; kk < 2; ++kk) {
      short8 af[4];
      #pragma unroll
      for (int m = 0; m < 4; ++m) {
        const int r = wm * 64 + m * 16 + (lane & 15);
        const int cb = (kk * 64 + ((lane >> 4) * 16)) ^ ((r & 7) << 4);
        af[m] = *(const short8*)(ab + r * 128 + cb);
      }
      #pragma unroll
      for (int nf = 0; nf < 4; ++nf) {
        const int n = wn * 64 + nf * 16 + (lane & 15);
        const int cb = (kk * 64 + ((lane >> 4) * 16)) ^ wswz(n);
        short8 bw = *(const short8*)((const char*)Wlds + n * 128 + cb);
        #pragma unroll
        for (int m = 0; m < 4; ++m) acc[m][nf] = mfma16(af[m], bw, acc[m][nf]);
      }
    }
  };

  stageA(0);
  loadW(0);
  writeW();
  __syncthreads();

  #pragma unroll 1
  for (int kt = 0; kt < IDIM / BK - 1; ++kt) {
    stageA(kt + 1);
    loadW(kt + 1);
    compute(kt);
    __syncthreads();
    writeW();
    __syncthreads();
  }
  compute(IDIM / BK - 1);

  #pragma unroll
  for (int m = 0; m < 4; ++m)
    #pragma unroll
    for (int nf = 0; nf < 4; ++nf) {
      const int col = n0 + wn * 64 + nf * 16 + (lane & 15);
      #pragma unroll
      for (int j = 0; j < 4; ++j) {
        const int row = row0 + wm * 64 + m * 16 + ((lane >> 4) * 4) + j;
        const float v = acc[m][nf][j];
        if constexpr (ROUTED) {
          if (row < row_end) {
            const int t = perm[row];
            out[(size_t)t * H + col] += v;     // shared pass wrote first
          }
        } else {
          out[(size_t)row * H + col] = v;
        }
      }
    }
}

// ---- launch --------------------------------------------------------------

extern "C" void kernel_launch(void* const* d_in, const int* in_sizes, int n_in,
                              void* d_out, int out_size, void* d_ws, size_t ws_size,
                              hipStream_t stream) {
  (void)in_sizes; (void)n_in; (void)out_size; (void)ws_size;
  const float* x      = (const float*)d_in[0];
  const float* gate_w = (const float*)d_in[1];
  const float* sgw    = (const float*)d_in[2];
  const float* suw    = (const float*)d_in[3];
  const float* sdw    = (const float*)d_in[4];
  const float* rgw    = (const float*)d_in[5];
  const float* ruw    = (const float*)d_in[6];
  const float* rdw    = (const float*)d_in[7];
  float* out = (float*)d_out;

  char* ws = (char*)d_ws;
  unsigned short* xbf  = (unsigned short*)(ws + 0);           // 16MB
  unsigned short* xsbf = (unsigned short*)(ws + 16777216);    // 16MB
  unsigned short* act  = (unsigned short*)(ws + 33554432);    // 32MB
  int* perm      = (int*)(ws + 67108864);                     // 32KB
  int* expert_id = (int*)(ws + 67141632);                     // 32KB
  int* counts    = (int*)(ws + 67174400);
  int* offsets   = (int*)(ws + 67174528);
  int* cursor    = (int*)(ws + 67174784);
  int* tile_e    = (int*)(ws + 67174912);
  int* tile_p    = (int*)(ws + 67175424);
  int* n_tiles   = (int*)(ws + 67175936);

  hipMemsetAsync(counts, 0, NE * sizeof(int), stream);
  router_kernel<<<TOK / 8, 256, 0, stream>>>(x, gate_w, xbf, xsbf, expert_id, counts);
  scan_kernel<<<1, 64, 0, stream>>>(counts, offsets, cursor, tile_e, tile_p, n_tiles);
  perm_kernel<<<TOK / 256, 256, 0, stream>>>(expert_id, cursor, perm);

  gateup_kernel<false><<<dim3(TOK / BM, IDIM / BN), 256, 0, stream>>>(
      xbf, sgw, suw, act, perm, tile_e, tile_p, offsets, n_tiles);
  down_kernel<false><<<dim3(TOK / BM, H / BN), 256, 0, stream>>>(
      act, sdw, out, perm, tile_e, tile_p, offsets, n_tiles);
  gateup_kernel<true><<<dim3(MAX_TILES, IDIM / BN), 256, 0, stream>>>(
      xsbf, rgw, ruw, act, perm, tile_e, tile_p, offsets, n_tiles);
  down_kernel<true><<<dim3(MAX_TILES, H / BN), 256, 0, stream>>>(
      act, rdw, out, perm, tile_e, tile_p, offsets, n_tiles);
}